// Round 1
// 149.486 us; speedup vs baseline: 1.0133x; 1.0133x over previous
//
#include <hip/hip_runtime.h>
#include <stdint.h>

// ---- types ----
typedef _Float16 f16x8 __attribute__((ext_vector_type(8)));
typedef _Float16 f16x4 __attribute__((ext_vector_type(4)));
typedef __fp16 h16x2 __attribute__((ext_vector_type(2)));  // cvt_pkrtz return type
typedef float f32x4 __attribute__((ext_vector_type(4)));
typedef float f32x16 __attribute__((ext_vector_type(16)));

#define SEQ 2048
#define NHEADS 8

// async global->LDS, 16B per lane, LDS dest = wave-uniform base + lane*16
#define GLOAD_LDS16(gp, lp)                                                        \
  __builtin_amdgcn_global_load_lds(                                                \
      (const __attribute__((address_space(1))) void*)(uintptr_t)(const void*)(gp), \
      (__attribute__((address_space(3))) void*)(uintptr_t)(void*)(lp), 16, 0, 0)

// barrier that waits LDS ops only (no vmem drain)
__device__ __forceinline__ void barrier_lds() {
  __builtin_amdgcn_s_waitcnt(0xc07f);  // lgkmcnt(0)
  __builtin_amdgcn_s_barrier();
}

__device__ __forceinline__ f16x4 pack4(float a, float b, float c, float d) {
  h16x2 lo = __builtin_amdgcn_cvt_pkrtz(a, b);
  h16x2 hi = __builtin_amdgcn_cvt_pkrtz(c, d);
  f16x4 o;
  o.x = (_Float16)lo.x; o.y = (_Float16)lo.y;
  o.z = (_Float16)hi.x; o.w = (_Float16)hi.y;
  return o;
}

// ---------------- fp32 -> f16 convert (x + 4 weights, one launch) ----------------
__global__ void cvt_all_kernel(const float* __restrict__ x, const float* __restrict__ wq,
                               const float* __restrict__ wk, const float* __restrict__ wv,
                               const float* __restrict__ wo, _Float16* __restrict__ xh,
                               _Float16* __restrict__ wh) {
  int i = blockIdx.x * 256 + threadIdx.x;  // 0 .. 1310719 (f4 units)
  const float* src;
  _Float16* dst;
  int off;
  if (i < 1048576) {
    src = x; dst = xh; off = i;
  } else {
    int j = i - 1048576;
    int sel = j >> 16;
    off = j & 65535;
    src = (sel == 0) ? wq : (sel == 1) ? wk : (sel == 2) ? wv : wo;
    dst = wh + (size_t)sel * 262144;
  }
  float4 v = ((const float4*)src)[off];
  ((f16x4*)dst)[off] = pack4(v.x, v.y, v.z, v.w);
}

// ---------------- shared 128x128 B^T GEMM tile core (f16, double-buffered DMA) ----------------
// lds = 64 KB: buf b at lds + b*16384: As[128][64], Bs[128][64].
// One __syncthreads per kt; next tile's DMA in flight across the whole compute.
__device__ __forceinline__ void gemm_tile_bt(const _Float16* __restrict__ A,
                                             const _Float16* __restrict__ B,
                                             int m0, int n0,
                                             _Float16* lds,
                                             f32x4 (&acc)[4][4]) {
  const int tid = threadIdx.x;
  const int w = tid >> 6, lane = tid & 63;
  const int wr = w >> 1, wc = w & 1;
  const int lrow = lane & 15, q = lane >> 4;
  const int snb = w * 32 + (lane >> 3);
  const int scb = lane & 7;

#pragma unroll
  for (int i = 0; i < 4; ++i)
#pragma unroll
    for (int j = 0; j < 4; ++j)
#pragma unroll
      for (int r = 0; r < 4; ++r) acc[i][j][r] = 0.f;

  // issue kt=0 staging
#pragma unroll
  for (int t = 0; t < 4; ++t) {
    int n = snb + t * 8;
    int cbg = scb ^ (n & 7);
    GLOAD_LDS16(A + (size_t)(m0 + n) * 512 + cbg * 8, lds + (w * 32 + t * 8) * 64);
    GLOAD_LDS16(B + (size_t)(n0 + n) * 512 + cbg * 8, lds + 8192 + (w * 32 + t * 8) * 64);
  }

  for (int kt = 0; kt < 8; ++kt) {  // K=512, BK=64
    __syncthreads();  // kt's DMA landed; prior reads of this buf done
    if (kt < 7) {
      _Float16* nb = lds + ((kt + 1) & 1) * 16384;
#pragma unroll
      for (int t = 0; t < 4; ++t) {
        int n = snb + t * 8;
        int cbg = scb ^ (n & 7);
        GLOAD_LDS16(A + (size_t)(m0 + n) * 512 + (kt + 1) * 64 + cbg * 8, nb + (w * 32 + t * 8) * 64);
        GLOAD_LDS16(B + (size_t)(n0 + n) * 512 + (kt + 1) * 64 + cbg * 8, nb + 8192 + (w * 32 + t * 8) * 64);
      }
    }
    _Float16* As = lds + (kt & 1) * 16384;
    _Float16* Bs = As + 8192;

    f16x8 af[4][2], bfr[4][2];
#pragma unroll
    for (int i = 0; i < 4; ++i) {
      int m = wr * 64 + i * 16 + lrow;
#pragma unroll
      for (int kk = 0; kk < 2; ++kk) {
        int cb = (kk * 4 + q) ^ (m & 7);
        af[i][kk] = *(const f16x8*)(As + m * 64 + cb * 8);
      }
    }
#pragma unroll
    for (int j = 0; j < 4; ++j) {
      int n = wc * 64 + j * 16 + lrow;
#pragma unroll
      for (int kk = 0; kk < 2; ++kk) {
        int cb = (kk * 4 + q) ^ (n & 7);
        bfr[j][kk] = *(const f16x8*)(Bs + n * 64 + cb * 8);
      }
    }
#pragma unroll
    for (int i = 0; i < 4; ++i)
#pragma unroll
      for (int j = 0; j < 4; ++j) {
        acc[i][j] = __builtin_amdgcn_mfma_f32_16x16x32_f16(af[i][0], bfr[j][0], acc[i][j], 0, 0, 0);
        acc[i][j] = __builtin_amdgcn_mfma_f32_16x16x32_f16(af[i][1], bfr[j][1], acc[i][j], 0, 0, 0);
      }
  }
}

// ---------------- QKV projection (768 blocks, coalesced bounce epilogues) ----------------
__global__ __launch_bounds__(256, 2) void qkv_kernel(
    const _Float16* __restrict__ xb, const _Float16* __restrict__ Wq,
    const _Float16* __restrict__ Wk, const _Float16* __restrict__ Wv,
    _Float16* __restrict__ Qo, _Float16* __restrict__ Ko, _Float16* __restrict__ Vto) {
  __shared__ _Float16 pool[32768];  // 64 KB dbuf staging; bounce [128][136] aliases
  const int z = blockIdx.z;
  f32x4 acc[4][4];
  const int tid = threadIdx.x, w = tid >> 6, lane = tid & 63;
  const int wr = w >> 1, wc = w & 1, lcol = lane & 15, q = lane >> 4;

  if (z < 2) {
    const int m0 = blockIdx.y * 128;  // out-feature tile
    const int n0 = blockIdx.x * 128;  // s tile
    gemm_tile_bt((z == 0) ? Wq : Wk, xb, m0, n0, pool, acc);
    _Float16* outp = (z == 0) ? Qo : Ko;
    __syncthreads();  // all reads done; reuse pool as bounce [s 128][c 136]
#pragma unroll
    for (int i = 0; i < 4; ++i) {
      int cl = wr * 64 + i * 16 + q * 4;
#pragma unroll
      for (int j = 0; j < 4; ++j) {
        int s = wc * 64 + j * 16 + lcol;
        *(f16x4*)(pool + s * 136 + cl) =
            pack4(acc[i][j][0], acc[i][j][1], acc[i][j][2], acc[i][j][3]);
      }
    }
    __syncthreads();
#pragma unroll
    for (int it = 0; it < 16; ++it) {
      int srow = it * 8 + (tid >> 5);
      int ch = tid & 31;
      f16x4 v = *(const f16x4*)(pool + srow * 136 + ch * 4);
      *(f16x4*)(outp + (size_t)(n0 + srow) * 512 + m0 + ch * 4) = v;
    }
  } else {
    const int m0 = blockIdx.x * 128;  // s tile
    const int n0 = blockIdx.y * 128;  // feature tile
    gemm_tile_bt(xb, Wv, m0, n0, pool, acc);
    const int bb = m0 >> 11, sl0 = m0 & 2047;
    __syncthreads();  // bounce [c 128][s 136]
#pragma unroll
    for (int i = 0; i < 4; ++i) {
      int s0 = wr * 64 + i * 16 + q * 4;
#pragma unroll
      for (int j = 0; j < 4; ++j) {
        int c = wc * 64 + j * 16 + lcol;
        *(f16x4*)(pool + c * 136 + s0) =
            pack4(acc[i][j][0], acc[i][j][1], acc[i][j][2], acc[i][j][3]);
      }
    }
    __syncthreads();
#pragma unroll
    for (int it = 0; it < 16; ++it) {
      int crow = it * 8 + (tid >> 5);
      int ch = tid & 31;
      int cg = n0 + crow, h = cg >> 6, d = cg & 63;
      f16x4 v = *(const f16x4*)(pool + crow * 136 + ch * 4);
      *(f16x4*)(Vto + ((size_t)((bb * NHEADS + h) * 64 + d)) * SEQ + sl0 + ch * 4) = v;
    }
  }
}

// ---------------- sigmoid attention: 32x32x16 MFMA everywhere ----------------
// Wave owns 32 q-rows. Swapped QK^T (S^T = K.Q^T) via mfma_32x32x16 with the K A-frag
// rows loaded in bit2<->bit3-swapped order, so the S^T C-regs land such that the PV
// A-frag for k-window w is simply cvt_pkrtz of regs [8w..8w+7] in order — no cross-lane
// ops. PV also 32x32x16 (full rate). K/V double-buffered; DMA for kt+1 issued right
// after the barrier -> full compute phase to land.
__global__ __launch_bounds__(256, 2) void attn_kernel(
    const _Float16* __restrict__ Qw, const _Float16* __restrict__ Kw,
    const _Float16* __restrict__ Vtw, _Float16* __restrict__ Ow) {
  __shared__ _Float16 lds[32768];  // 64 KB: buf b at lds+b*16384: Ks[128][64], Vts[64][128]

  const int tid = threadIdx.x, w = tid >> 6, lane = tid & 63;
  const int q31 = lane & 31, hi = lane >> 5;

  // XCD swizzle: 4 bh x 16 q-tiles per XCD (K/V stay L2-resident)
  const int L = blockIdx.x;
  const int xcd = L & 7, slot = L >> 3;
  const int bh = xcd * 4 + (slot >> 4), qt = slot & 15;
  const int b = bh >> 3, h = bh & 7;
  const int q0 = qt * 128;

  const _Float16* Qp = Qw + ((size_t)(b * SEQ + q0)) * 512 + h * 64;
  const _Float16* Kp = Kw + ((size_t)b * SEQ) * 512 + h * 64;
  const _Float16* Vp = Vtw + (size_t)bh * 64 * SEQ;

  const int snb = w * 32 + (lane >> 3), scb = lane & 7;   // [128][64] staging
  const int vnb = w * 16 + (lane >> 4), vcb = lane & 15;  // [64][128] staging

  // stage Q tile [128][64] into buf0's Ks region
  _Float16* Qs = lds;
#pragma unroll
  for (int t = 0; t < 4; ++t) {
    int n = snb + t * 8;
    int cbg = scb ^ (n & 7);
    GLOAD_LDS16(Qp + (size_t)n * 512 + cbg * 8, Qs + (w * 32 + t * 8) * 64);
  }
  __syncthreads();

  // wave's own 32 q-rows: Q B-frags per d-slice s (lane: col=q31, d=s*16+hi*8+j)
  f16x8 qb[4];
  const int qrow = w * 32 + q31;
#pragma unroll
  for (int s = 0; s < 4; ++s) {
    int cb = (s * 2 + hi) ^ (qrow & 7);
    qb[s] = *(const f16x8*)(Qs + qrow * 64 + cb * 8);
  }
  barrier_lds();  // all qb reads done before buf0 DMA overwrite

  // issue kt=0 staging into buf0
#pragma unroll
  for (int t = 0; t < 4; ++t) {
    int n = snb + t * 8;
    int cbg = scb ^ (n & 7);
    GLOAD_LDS16(Kp + (size_t)n * 512 + cbg * 8, lds + (w * 32 + t * 8) * 64);
  }
#pragma unroll
  for (int t = 0; t < 4; ++t) {
    int nv = vnb + t * 4;
    int cbg = vcb ^ (nv & 15);
    GLOAD_LDS16(Vp + (size_t)nv * SEQ + cbg * 8, lds + 8192 + (w * 16 + t * 4) * 128);
  }

  f32x16 oacc[2];
  f32x16 z16;
#pragma unroll
  for (int r = 0; r < 16; ++r) { z16[r] = 0.f; oacc[0][r] = 0.f; oacc[1][r] = 0.f; }

  // K A-frag lane->row permutation: swap bits 2 and 3 of (lane&31).
  // With this, S^T C-reg r on lane-half hi holds k = m*32 + 8*(r>>3)*2 ... i.e. the
  // PV A-frag for k-window w is regs [8w..8w+7] packed in order.
  const int klp = (q31 & 3) | ((q31 & 4) << 1) | ((q31 & 8) >> 1) | (q31 & 16);

  const float c1 = 0.18033688011112042f;  // (1/8)*log2(e); exp2 bias -1 = -11+10 (P x1024)

  for (int kt = 0; kt < 16; ++kt) {
    __syncthreads();  // kt's DMA landed (issued one iter ago); prev buf reads done
    if (kt < 15) {
      _Float16* nb = lds + ((kt + 1) & 1) * 16384;
#pragma unroll
      for (int t = 0; t < 4; ++t) {
        int n = snb + t * 8;
        int cbg = scb ^ (n & 7);
        GLOAD_LDS16(Kp + (size_t)((kt + 1) * 128 + n) * 512 + cbg * 8, nb + (w * 32 + t * 8) * 64);
      }
#pragma unroll
      for (int t = 0; t < 4; ++t) {
        int nv = vnb + t * 4;
        int cbg = vcb ^ (nv & 15);
        GLOAD_LDS16(Vp + (size_t)nv * SEQ + (kt + 1) * 128 + cbg * 8, nb + 8192 + (w * 16 + t * 4) * 128);
      }
    }
    _Float16* Ksc = lds + (kt & 1) * 16384;
    _Float16* Vtsc = Ksc + 8192;

    // 4 windows of 32 k each: QK^T (S^T, 4 MFMA) -> sigmoid(16 regs) -> PV (4 MFMA)
#pragma unroll
    for (int m = 0; m < 4; ++m) {
      const int krow = m * 32 + klp;
      f16x8 ka[4];
#pragma unroll
      for (int s = 0; s < 4; ++s) {
        int cb = (s * 2 + hi) ^ (krow & 7);
        ka[s] = *(const f16x8*)(Ksc + krow * 64 + cb * 8);
      }
      // V B-frags (lane: col=d=q31 within tile t, k = win*16 + hi*8 + j)
      f16x8 vb[2][2];
#pragma unroll
      for (int ww = 0; ww < 2; ++ww)
#pragma unroll
        for (int t = 0; t < 2; ++t) {
          int drow = t * 32 + q31;
          int g = m * 4 + ww * 2 + hi;
          int cb = g ^ (drow & 15);
          vb[ww][t] = *(const f16x8*)(Vtsc + drow * 128 + cb * 8);
        }

      f32x16 sacc = __builtin_amdgcn_mfma_f32_32x32x16_f16(ka[0], qb[0], z16, 0, 0, 0);
      sacc = __builtin_amdgcn_mfma_f32_32x32x16_f16(ka[1], qb[1], sacc, 0, 0, 0);
      sacc = __builtin_amdgcn_mfma_f32_32x32x16_f16(ka[2], qb[2], sacc, 0, 0, 0);
      sacc = __builtin_amdgcn_mfma_f32_32x32x16_f16(ka[3], qb[3], sacc, 0, 0, 0);

      float p[16];
#pragma unroll
      for (int r = 0; r < 16; ++r) {
        float wp = __builtin_amdgcn_exp2f(__builtin_fmaf(sacc[r], c1, -1.0f));
        float e = wp * 0.0009765625f;
        p[r] = __builtin_fmaf(wp, __builtin_fmaf(e, e, -e), wp);  // wp*(1-e+e^2)
      }

      f16x8 pa[2];
#pragma unroll
      for (int ww = 0; ww < 2; ++ww) {
        h16x2 a0 = __builtin_amdgcn_cvt_pkrtz(p[8 * ww + 0], p[8 * ww + 1]);
        h16x2 a1 = __builtin_amdgcn_cvt_pkrtz(p[8 * ww + 2], p[8 * ww + 3]);
        h16x2 a2 = __builtin_amdgcn_cvt_pkrtz(p[8 * ww + 4], p[8 * ww + 5]);
        h16x2 a3 = __builtin_amdgcn_cvt_pkrtz(p[8 * ww + 6], p[8 * ww + 7]);
        pa[ww][0] = (_Float16)a0.x; pa[ww][1] = (_Float16)a0.y;
        pa[ww][2] = (_Float16)a1.x; pa[ww][3] = (_Float16)a1.y;
        pa[ww][4] = (_Float16)a2.x; pa[ww][5] = (_Float16)a2.y;
        pa[ww][6] = (_Float16)a3.x; pa[ww][7] = (_Float16)a3.y;
      }

      oacc[0] = __builtin_amdgcn_mfma_f32_32x32x16_f16(pa[0], vb[0][0], oacc[0], 0, 0, 0);
      oacc[1] = __builtin_amdgcn_mfma_f32_32x32x16_f16(pa[0], vb[0][1], oacc[1], 0, 0, 0);
      oacc[0] = __builtin_amdgcn_mfma_f32_32x32x16_f16(pa[1], vb[1][0], oacc[0], 0, 0, 0);
      oacc[1] = __builtin_amdgcn_mfma_f32_32x32x16_f16(pa[1], vb[1][1], oacc[1], 0, 0, 0);
    }
  }

  // epilogue: descale, bounce through LDS, coalesced 128B row stores
  barrier_lds();       // all waves' LDS reads done; no DMA outstanding (kt=15 skipped)
  _Float16* Ob = lds;  // [128][72]
#pragma unroll
  for (int t = 0; t < 2; ++t) {
#pragma unroll
    for (int r = 0; r < 16; ++r) {
      int row = w * 32 + (r & 3) + ((r >> 2) << 3) + hi * 4;
      int d = t * 32 + q31;
      Ob[row * 72 + d] = (_Float16)(oacc[t][r] * 0.0009765625f);
    }
  }
  barrier_lds();
#pragma unroll
  for (int it = 0; it < 8; ++it) {
    int row = it * 16 + (tid >> 4);
    int ch = tid & 15;
    f16x4 v = *(const f16x4*)(Ob + row * 72 + ch * 4);
    *(f16x4*)(Ow + (size_t)(b * SEQ + q0 + row) * 512 + h * 64 + ch * 4) = v;
  }
}

// ---------------- output projection (fp32 out, coalesced) ----------------
__global__ __launch_bounds__(256, 2) void oproj_kernel(
    const _Float16* __restrict__ A, const _Float16* __restrict__ Wo,
    float* __restrict__ out) {
  __shared__ _Float16 pool[32768];  // 64 KB dbuf
  const int m0 = blockIdx.x * 128, n0 = blockIdx.y * 128;
  f32x4 acc[4][4];
  gemm_tile_bt(A, Wo, m0, n0, pool, acc);

  const int tid = threadIdx.x, w = tid >> 6, lane = tid & 63;
  const int wr = w >> 1, wc = w & 1, lcol = lane & 15, q = lane >> 4;
#pragma unroll
  for (int i = 0; i < 4; ++i) {
    int gm0 = m0 + wr * 64 + i * 16 + q * 4;
#pragma unroll
    for (int j = 0; j < 4; ++j) {
      int gn = n0 + wc * 64 + j * 16 + lcol;
#pragma unroll
      for (int r = 0; r < 4; ++r)
        out[(size_t)(gm0 + r) * 512 + gn] = acc[i][j][r];
    }
  }
}

// ---------------- launch ----------------
extern "C" void kernel_launch(void* const* d_in, const int* in_sizes, int n_in,
                              void* d_out, int out_size, void* d_ws, size_t ws_size,
                              hipStream_t stream) {
  const float* x = (const float*)d_in[0];
  const float* Wq = (const float*)d_in[1];
  const float* Wk = (const float*)d_in[2];
  const float* Wv = (const float*)d_in[3];
  const float* Wo = (const float*)d_in[4];
  float* out = (float*)d_out;
  char* ws = (char*)d_ws;

  _Float16* xh = (_Float16*)(ws + 0);          // 8 MB [8192][512]
  _Float16* wh = (_Float16*)(ws + 8388608);    // 4 x 512 KB (q,k,v,o)
  _Float16* Qw = (_Float16*)(ws + 10485760);   // 8 MB [8192][512]
  _Float16* Kw = (_Float16*)(ws + 18874368);   // 8 MB [8192][512]
  _Float16* Vtw = (_Float16*)(ws + 27262976);  // 8 MB [B,H,D,S]
  _Float16* Ow = (_Float16*)(ws + 35651584);   // 8 MB [8192][512]

  _Float16* wqh = wh;
  _Float16* wkh = wh + 262144;
  _Float16* wvh = wh + 524288;
  _Float16* woh = wh + 786432;

  cvt_all_kernel<<<5120, 256, 0, stream>>>(x, Wq, Wk, Wv, Wo, xh, wh);
  qkv_kernel<<<dim3(64, 4, 3), 256, 0, stream>>>(xh, wqh, wkh, wvh, Qw, Kw, Vtw);
  attn_kernel<<<512, 256, 0, stream>>>(Qw, Kw, Vtw, Ow);
  oproj_kernel<<<dim3(64, 4), 256, 0, stream>>>(Ow, woh, out);
}